// Round 3
// baseline (525.154 us; speedup 1.0000x reference)
//
#include <hip/hip_runtime.h>
#include <hip/hip_bf16.h>

#define B_   64
#define S_   2048
#define H_   256
#define H3_  768
#define K_   512            // 2H (static+dynamic)
#define MT   128            // M tile (positions per workgroup)

typedef __attribute__((ext_vector_type(8))) short  bf16x8;
typedef __attribute__((ext_vector_type(4))) float  f32x4;

__device__ __forceinline__ ushort f2bf(float f) {
    __hip_bfloat16 h = __float2bfloat16(f);
    return *reinterpret_cast<ushort*>(&h);
}

__device__ __forceinline__ float fast_tanh(float x) {
    float e = __expf(2.0f * x);
    return 1.0f - 2.0f / (e + 1.0f);
}

// ---------------- kernel 1: pack W[:, 0:512] to bf16 in FRAGMENT order.
// Layout: [ot(48)][ks(16)][lane(64)][j(8)]
//   o = ot*16 + (lane&15), k = ks*32 + (lane>>4)*8 + j
__global__ void pack_w(const float* __restrict__ W, short* __restrict__ wpk) {
    int t = blockIdx.x * 256 + threadIdx.x;       // over 48*16*64
    if (t >= 48 * 16 * 64) return;
    int lane = t & 63;
    int ks   = (t >> 6) & 15;
    int ot   = t >> 10;
    int o  = ot * 16 + (lane & 15);
    int kb = ks * 32 + (lane >> 4) * 8;
    const float* src = W + (size_t)o * H3_ + kb;
    float4 a = ((const float4*)src)[0];
    float4 b = ((const float4*)src)[1];
    union { bf16x8 v; uint4 u; } pk;
    pk.u.x = (uint)f2bf(a.x) | ((uint)f2bf(a.y) << 16);
    pk.u.y = (uint)f2bf(a.z) | ((uint)f2bf(a.w) << 16);
    pk.u.z = (uint)f2bf(b.x) | ((uint)f2bf(b.y) << 16);
    pk.u.w = (uint)f2bf(b.z) | ((uint)f2bf(b.w) << 16);
    *(bf16x8*)(wpk + (size_t)t * 8) = pk.v;
}

// ---------------- kernel 2: bias[b,o] = sum_k W[o,512+k] * dec[b,k]  (fp32)
__global__ void bias_k(const float* __restrict__ W, const float* __restrict__ dec,
                       float* __restrict__ bias) {
    int idx = blockIdx.x * 256 + threadIdx.x;     // over 64*768
    if (idx >= B_ * H3_) return;
    int b = idx / H3_;
    int o = idx - b * H3_;
    const float4* wr = (const float4*)(W + (size_t)o * H3_ + 2 * H_);
    const float4* dv = (const float4*)(dec + (size_t)b * H_);
    float s = 0.f;
#pragma unroll 8
    for (int k = 0; k < H_ / 4; ++k) {
        float4 a = wr[k], d = dv[k];
        s += a.x * d.x + a.y * d.y + a.z * d.z + a.w * d.w;
    }
    bias[idx] = s;
}

// ---------------- kernel 3: fused score GEMM, M=128, 8 waves, full-K LDS
// LDS A: [q(4)][row(128)][klocal(128)] bf16, 32 KB per quarter = 128 KB.
// Pass p in {0,1}: wave covers cols  wave*96 + p*48 .. +47  (3 o-tiles).
// Pass 0 streams quarters (stage q+1 while computing q); pass 1 runs on
// resident LDS with zero barriers.
__global__ __launch_bounds__(512, 2)
void score_k(const float* __restrict__ stat, const float* __restrict__ dyn,
             const short* __restrict__ wpk, const float* __restrict__ bias,
             const float* __restrict__ v, float* __restrict__ scores) {
    __shared__ short aT[4 * MT * 128];       // 128 KB
    __shared__ float sred[8][MT];            // 4 KB

    const int tid  = threadIdx.x;
    const int pos0 = blockIdx.x * MT;
    const int bidx = pos0 >> 11;             // /2048 ; tile never crosses b

    // ---- staging helpers (quarter = 128 rows x 128 k fp32 = 64 KB read)
    // per thread: 4 units of 8 floats = 8 float4 loads in flight.
    float4 f0[4], f1[4];
    auto stage_load = [&](int q) {
#pragma unroll
        for (int u = 0; u < 4; ++u) {
            int lin = u * 512 + tid;
            int row = lin >> 4;              // 16 units per row
            int kl  = (lin & 15) * 8;        // local k
            const float* src = (q < 2)
                ? (stat + (size_t)(pos0 + row) * H_ + q * 128 + kl)
                : (dyn  + (size_t)(pos0 + row) * H_ + (q - 2) * 128 + kl);
            f0[u] = ((const float4*)src)[0];
            f1[u] = ((const float4*)src)[1];
        }
    };
    auto stage_write = [&](int q) {
#pragma unroll
        for (int u = 0; u < 4; ++u) {
            int lin = u * 512 + tid;
            int row = lin >> 4;
            int kl  = (lin & 15) * 8;
            uint4 pk;
            pk.x = (uint)f2bf(f0[u].x) | ((uint)f2bf(f0[u].y) << 16);
            pk.y = (uint)f2bf(f0[u].z) | ((uint)f2bf(f0[u].w) << 16);
            pk.z = (uint)f2bf(f1[u].x) | ((uint)f2bf(f1[u].y) << 16);
            pk.w = (uint)f2bf(f1[u].z) | ((uint)f2bf(f1[u].w) << 16);
            int off = q * 32768 + row * 256 + kl * 2;
            off ^= (row & 7) << 4;           // bank-conflict swizzle
            *(uint4*)((char*)aT + off) = pk;
        }
    };

    // prologue: stage quarter 0
    stage_load(0);
    stage_write(0);
    __syncthreads();

    const int wave = tid >> 6;
    const int lane = tid & 63;
    const int lr = lane & 15;                // A: row-in-16 ; B/C: col-in-16
    const int lg = lane >> 4;                // k-group (8 elems each)

    float sacc[8][4];
#pragma unroll
    for (int mi = 0; mi < 8; ++mi)
#pragma unroll
        for (int j = 0; j < 4; ++j) sacc[mi][j] = 0.f;

    for (int p = 0; p < 2; ++p) {
        f32x4 acc[8][3];
#pragma unroll
        for (int mi = 0; mi < 8; ++mi)
#pragma unroll
            for (int ni = 0; ni < 3; ++ni) acc[mi][ni] = (f32x4)0.f;

#pragma unroll
        for (int q = 0; q < 4; ++q) {
            if (p == 0 && q < 3) stage_load(q + 1);   // overlap with compute
#pragma unroll
            for (int ksl = 0; ksl < 4; ++ksl) {
                const int ks = q * 4 + ksl;
                bf16x8 bfr[3];
#pragma unroll
                for (int ni = 0; ni < 3; ++ni) {
                    int ot = wave * 6 + p * 3 + ni;
                    bfr[ni] = *(const bf16x8*)(wpk +
                        ((size_t)(ot * 16 + ks) * 64 + lane) * 8);
                }
                const int kbl = ksl * 32 + lg * 8;    // local k base
#pragma unroll
                for (int mi = 0; mi < 8; ++mi) {
                    int row = mi * 16 + lr;
                    int off = q * 32768 + row * 256 + kbl * 2;
                    off ^= (row & 7) << 4;
                    bf16x8 afr = *(const bf16x8*)((const char*)aT + off);
#pragma unroll
                    for (int ni = 0; ni < 3; ++ni)
                        acc[mi][ni] = __builtin_amdgcn_mfma_f32_16x16x32_bf16(
                            afr, bfr[ni], acc[mi][ni], 0, 0, 0);
                }
            }
            if (p == 0 && q < 3) {
                stage_write(q + 1);
                __syncthreads();
            }
        }

        // epilogue: sacc += v * tanh(acc + bias)
#pragma unroll
        for (int ni = 0; ni < 3; ++ni) {
            int o = wave * 96 + p * 48 + ni * 16 + lr;
            float bv = bias[bidx * H3_ + o];
            float vv = v[o];
#pragma unroll
            for (int mi = 0; mi < 8; ++mi)
#pragma unroll
                for (int j = 0; j < 4; ++j)
                    sacc[mi][j] += vv * fast_tanh(acc[mi][ni][j] + bv);
        }
    }

    // reduce over the 16 column-lanes (lr); rows live at mi*16 + lg*4 + j
#pragma unroll
    for (int mi = 0; mi < 8; ++mi)
#pragma unroll
        for (int j = 0; j < 4; ++j) {
            float x = sacc[mi][j];
            x += __shfl_xor(x, 1);
            x += __shfl_xor(x, 2);
            x += __shfl_xor(x, 4);
            x += __shfl_xor(x, 8);
            sacc[mi][j] = x;
        }
    if (lr == 0) {
#pragma unroll
        for (int mi = 0; mi < 8; ++mi)
#pragma unroll
            for (int j = 0; j < 4; ++j)
                sred[wave][mi * 16 + lg * 4 + j] = sacc[mi][j];
    }
    __syncthreads();
    if (tid < MT) {
        float s = 0.f;
#pragma unroll
        for (int w = 0; w < 8; ++w) s += sred[w][tid];
        scores[pos0 + tid] = s;
    }
}

// ---------------- kernel 4: softmax over S=2048 per b, in place on d_out
__global__ void softmax_k(float* __restrict__ out) {
    const int b = blockIdx.x;
    float* row = out + (size_t)b * S_;
    const int tid  = threadIdx.x;          // 256
    const int wave = tid >> 6;
    const int lane = tid & 63;

    float vals[8];
    float m = -1e30f;
#pragma unroll
    for (int i = 0; i < 8; ++i) {
        vals[i] = row[tid + i * 256];
        m = fmaxf(m, vals[i]);
    }
#pragma unroll
    for (int off = 32; off >= 1; off >>= 1) m = fmaxf(m, __shfl_xor(m, off));
    __shared__ float redm[4];
    __shared__ float reds[4];
    if (lane == 0) redm[wave] = m;
    __syncthreads();
    m = fmaxf(fmaxf(redm[0], redm[1]), fmaxf(redm[2], redm[3]));

    float s = 0.f;
#pragma unroll
    for (int i = 0; i < 8; ++i) {
        vals[i] = __expf(vals[i] - m);
        s += vals[i];
    }
#pragma unroll
    for (int off = 32; off >= 1; off >>= 1) s += __shfl_xor(s, off);
    if (lane == 0) reds[wave] = s;
    __syncthreads();
    s = reds[0] + reds[1] + reds[2] + reds[3];
    float inv = 1.0f / s;
#pragma unroll
    for (int i = 0; i < 8; ++i) row[tid + i * 256] = vals[i] * inv;
}

extern "C" void kernel_launch(void* const* d_in, const int* in_sizes, int n_in,
                              void* d_out, int out_size, void* d_ws, size_t ws_size,
                              hipStream_t stream) {
    const float* stat = (const float*)d_in[0];   // [64,2048,256]
    const float* dyn  = (const float*)d_in[1];   // [64,2048,256]
    const float* dec  = (const float*)d_in[2];   // [64,256]
    const float* v    = (const float*)d_in[3];   // [1,768]
    const float* W    = (const float*)d_in[4];   // [768,768]
    float* out = (float*)d_out;                  // [64,2048]

    short* wpk  = (short*)d_ws;                                 // 786432 B
    float* bias = (float*)((char*)d_ws + (size_t)H3_ * K_ * 2); // 196608 B

    pack_w <<<(48 * 16 * 64 + 255) / 256, 256, 0, stream>>>(W, wpk);
    bias_k <<<(B_ * H3_ + 255) / 256, 256, 0, stream>>>(W, dec, bias);
    score_k<<<(B_ * S_) / MT, 512, 0, stream>>>(stat, dyn, wpk, bias, v, out);
    softmax_k<<<B_, 256, 0, stream>>>(out);
}

// Round 4
// 302.723 us; speedup vs baseline: 1.7348x; 1.7348x over previous
//
#include <hip/hip_runtime.h>
#include <hip/hip_bf16.h>

#define B_   64
#define S_   2048
#define H_   256
#define H3_  768
#define K_   512            // 2H (static+dynamic)
#define MT   64             // M tile (positions per tile)
#define PBLK 512            // persistent blocks; 4 tiles each

typedef __attribute__((ext_vector_type(8))) short  bf16x8;
typedef __attribute__((ext_vector_type(4))) float  f32x4;

__device__ __forceinline__ ushort f2bf(float f) {
    __hip_bfloat16 h = __float2bfloat16(f);
    return *reinterpret_cast<ushort*>(&h);
}
__device__ __forceinline__ uint pkbf(float a, float b) {
    return (uint)f2bf(a) | ((uint)f2bf(b) << 16);
}
__device__ __forceinline__ float fast_tanh(float x) {
    float e = __expf(2.0f * x);
    return 1.0f - 2.0f / (e + 1.0f);
}

// ---------------- kernel 1: pack W[:, 0:512] to bf16 in FRAGMENT order.
// Layout: [ot(48)][ks(16)][lane(64)][j(8)]
//   o = ot*16 + (lane&15), k = ks*32 + (lane>>4)*8 + j
__global__ void pack_w(const float* __restrict__ W, short* __restrict__ wpk) {
    int t = blockIdx.x * 256 + threadIdx.x;       // over 48*16*64
    if (t >= 48 * 16 * 64) return;
    int lane = t & 63;
    int ks   = (t >> 6) & 15;
    int ot   = t >> 10;
    int o  = ot * 16 + (lane & 15);
    int kb = ks * 32 + (lane >> 4) * 8;
    const float* src = W + (size_t)o * H3_ + kb;
    float4 a = ((const float4*)src)[0];
    float4 b = ((const float4*)src)[1];
    union { bf16x8 v; uint4 u; } pk;
    pk.u.x = pkbf(a.x, a.y);
    pk.u.y = pkbf(a.z, a.w);
    pk.u.z = pkbf(b.x, b.y);
    pk.u.w = pkbf(b.z, b.w);
    *(bf16x8*)(wpk + (size_t)t * 8) = pk.v;
}

// ---------------- kernel 2: bias[b,o] = sum_k W[o,512+k] * dec[b,k]  (fp32)
__global__ void bias_k(const float* __restrict__ W, const float* __restrict__ dec,
                       float* __restrict__ bias) {
    int idx = blockIdx.x * 256 + threadIdx.x;     // over 64*768
    if (idx >= B_ * H3_) return;
    int b = idx / H3_;
    int o = idx - b * H3_;
    const float4* wr = (const float4*)(W + (size_t)o * H3_ + 2 * H_);
    const float4* dv = (const float4*)(dec + (size_t)b * H_);
    float s = 0.f;
#pragma unroll 8
    for (int k = 0; k < H_ / 4; ++k) {
        float4 a = wr[k], d = dv[k];
        s += a.x * d.x + a.y * d.y + a.z * d.z + a.w * d.w;
    }
    bias[idx] = s;
}

// ---------------- kernel 3: fused score GEMM, persistent blocks,
// cross-tile staging pipeline (issue-early / convert-mid / write-late).
// Per tile: 4 passes x (ni=3 o-tiles per wave), zero barriers inside compute.
__global__ __launch_bounds__(256, 2)
void score_k(const float* __restrict__ stat, const float* __restrict__ dyn,
             const short* __restrict__ wpk, const float* __restrict__ bias,
             const float* __restrict__ v, float* __restrict__ scores) {
    __shared__ short aT[MT * K_];            // 64 KB, XOR-swizzled
    __shared__ float sred[4][MT];            // 1 KB

    const int tid  = threadIdx.x;
    const int wave = tid >> 6;
    const int lane = tid & 63;
    const int lr   = lane & 15;              // A: row-in-16 ; B/C: col-in-16
    const int lg   = lane >> 4;              // k-group (8 elems each)

    // staging geometry: unit u (0..15): row-in-tile = wave + u*4, k = lane*8
    const int kcol = lane * 8;
    const float* srcbase = (kcol < 256) ? (stat + kcol) : (dyn + (kcol - 256));

    float4 f0[4], f1[4];                     // one quarter (4 units) in flight
    uint4  pk[16];                           // full tile bf16, packed

    auto loadq = [&](int q, int gpos0) {
#pragma unroll
        for (int i = 0; i < 4; ++i) {
            int u = q * 4 + i;
            const float4* p = (const float4*)(srcbase + (size_t)(gpos0 + wave + u * 4) * H_);
            f0[i] = p[0];
            f1[i] = p[1];
        }
    };
    auto cvtq = [&](int q) {                 // q must be compile-time constant
#pragma unroll
        for (int i = 0; i < 4; ++i) {
            uint4 r;
            r.x = pkbf(f0[i].x, f0[i].y);
            r.y = pkbf(f0[i].z, f0[i].w);
            r.z = pkbf(f1[i].x, f1[i].y);
            r.w = pkbf(f1[i].z, f1[i].w);
            pk[q * 4 + i] = r;
        }
    };
    auto writeall = [&]() {
#pragma unroll
        for (int u = 0; u < 16; ++u) {
            int row = wave + u * 4;
            int off = ((row << 10) + (lane << 4)) ^ ((row & 7) << 4);
            *(uint4*)((char*)aT + off) = pk[u];
        }
    };

    // prologue: stage tile 0
    {
        const int g0 = blockIdx.x * MT;
#pragma unroll
        for (int q = 0; q < 4; ++q) { loadq(q, g0); cvtq(q); }
        writeall();
        __syncthreads();
    }

    const int swz = (lr & 7) << 4;

#pragma unroll 1
    for (int t = 0; t < 4; ++t) {
        const int tile  = blockIdx.x + PBLK * t;
        const int pos0  = tile * MT;
        const int bidx  = pos0 >> 11;
        const int pos0n = (blockIdx.x + PBLK * (t + 1)) * MT;   // used only if t<3

        float sacc[4][4];
#pragma unroll
        for (int mi = 0; mi < 4; ++mi)
#pragma unroll
            for (int j = 0; j < 4; ++j) sacc[mi][j] = 0.f;

#pragma unroll
        for (int p = 0; p < 4; ++p) {
            // cross-tile staging milestones (register-only, no barriers)
            if (t < 3) {
                if (p == 0)      { loadq(0, pos0n); }
                else if (p == 1) { cvtq(0); loadq(1, pos0n); }
                else if (p == 2) { cvtq(1); loadq(2, pos0n); }
                else             { cvtq(2); loadq(3, pos0n); }
            }

            f32x4 acc[4][3];
#pragma unroll
            for (int mi = 0; mi < 4; ++mi)
#pragma unroll
                for (int ni = 0; ni < 3; ++ni) acc[mi][ni] = (f32x4)0.f;

            const short* wp0 = wpk + ((size_t)((wave * 12 + p * 3) * 16) * 64 + lane) * 8;

#pragma unroll 4
            for (int ks = 0; ks < 16; ++ks) {
                bf16x8 bfr[3];
#pragma unroll
                for (int ni = 0; ni < 3; ++ni)
                    bfr[ni] = *(const bf16x8*)(wp0 + ni * 8192 + ks * 512);
                const int kb2 = ks * 64 + lg * 16;
#pragma unroll
                for (int mi = 0; mi < 4; ++mi) {
                    int off = (((mi * 16 + lr) << 10) + kb2) ^ swz;
                    bf16x8 afr = *(const bf16x8*)((const char*)aT + off);
#pragma unroll
                    for (int ni = 0; ni < 3; ++ni)
                        acc[mi][ni] = __builtin_amdgcn_mfma_f32_16x16x32_bf16(
                            afr, bfr[ni], acc[mi][ni], 0, 0, 0);
                }
            }

            // epilogue: sacc += v * tanh(acc + bias)
#pragma unroll
            for (int ni = 0; ni < 3; ++ni) {
                int o = wave * 192 + p * 48 + ni * 16 + lr;
                float bv = bias[bidx * H3_ + o];
                float vv = v[o];
#pragma unroll
                for (int mi = 0; mi < 4; ++mi)
#pragma unroll
                    for (int j = 0; j < 4; ++j)
                        sacc[mi][j] += vv * fast_tanh(acc[mi][ni][j] + bv);
            }
        }

        // reduce over the 16 column-lanes; rows live at mi*16 + lg*4 + j
#pragma unroll
        for (int mi = 0; mi < 4; ++mi)
#pragma unroll
            for (int j = 0; j < 4; ++j) {
                float x = sacc[mi][j];
                x += __shfl_xor(x, 1);
                x += __shfl_xor(x, 2);
                x += __shfl_xor(x, 4);
                x += __shfl_xor(x, 8);
                sacc[mi][j] = x;
            }
        if (lr == 0) {
#pragma unroll
            for (int mi = 0; mi < 4; ++mi)
#pragma unroll
                for (int j = 0; j < 4; ++j)
                    sred[wave][mi * 16 + lg * 4 + j] = sacc[mi][j];
        }
        __syncthreads();
        if (tid < MT) {
            float s = sred[0][tid] + sred[1][tid] + sred[2][tid] + sred[3][tid];
            scores[pos0 + tid] = s;
        }

        if (t < 3) {
            cvtq(3);
            writeall();          // safe: all waves passed the sync above
            __syncthreads();     // aT(t+1) visible before next compute
        }
    }
}

// ---------------- kernel 4: softmax over S=2048 per b, in place on d_out
__global__ void softmax_k(float* __restrict__ out) {
    const int b = blockIdx.x;
    float* row = out + (size_t)b * S_;
    const int tid  = threadIdx.x;          // 256
    const int wave = tid >> 6;
    const int lane = tid & 63;

    float vals[8];
    float m = -1e30f;
#pragma unroll
    for (int i = 0; i < 8; ++i) {
        vals[i] = row[tid + i * 256];
        m = fmaxf(m, vals[i]);
    }
#pragma unroll
    for (int off = 32; off >= 1; off >>= 1) m = fmaxf(m, __shfl_xor(m, off));
    __shared__ float redm[4];
    __shared__ float reds[4];
    if (lane == 0) redm[wave] = m;
    __syncthreads();
    m = fmaxf(fmaxf(redm[0], redm[1]), fmaxf(redm[2], redm[3]));

    float s = 0.f;
#pragma unroll
    for (int i = 0; i < 8; ++i) {
        vals[i] = __expf(vals[i] - m);
        s += vals[i];
    }
#pragma unroll
    for (int off = 32; off >= 1; off >>= 1) s += __shfl_xor(s, off);
    if (lane == 0) reds[wave] = s;
    __syncthreads();
    s = reds[0] + reds[1] + reds[2] + reds[3];
    float inv = 1.0f / s;
#pragma unroll
    for (int i = 0; i < 8; ++i) row[tid + i * 256] = vals[i] * inv;
}

extern "C" void kernel_launch(void* const* d_in, const int* in_sizes, int n_in,
                              void* d_out, int out_size, void* d_ws, size_t ws_size,
                              hipStream_t stream) {
    const float* stat = (const float*)d_in[0];   // [64,2048,256]
    const float* dyn  = (const float*)d_in[1];   // [64,2048,256]
    const float* dec  = (const float*)d_in[2];   // [64,256]
    const float* v    = (const float*)d_in[3];   // [1,768]
    const float* W    = (const float*)d_in[4];   // [768,768]
    float* out = (float*)d_out;                  // [64,2048]

    short* wpk  = (short*)d_ws;                                 // 786432 B
    float* bias = (float*)((char*)d_ws + (size_t)H3_ * K_ * 2); // 196608 B

    pack_w <<<(48 * 16 * 64 + 255) / 256, 256, 0, stream>>>(W, wpk);
    bias_k <<<(B_ * H3_ + 255) / 256, 256, 0, stream>>>(W, dec, bias);
    score_k<<<PBLK, 256, 0, stream>>>(stat, dyn, wpk, bias, v, out);
    softmax_k<<<B_, 256, 0, stream>>>(out);
}

// Round 5
// 198.032 us; speedup vs baseline: 2.6519x; 1.5287x over previous
//
#include <hip/hip_runtime.h>
#include <hip/hip_bf16.h>

#define B_   64
#define S_   2048
#define H_   256
#define H3_  768
#define K_   512            // 2H (static+dynamic)
#define MT   64             // M tile (positions per tile)
#define NBLK 256            // persistent blocks (1 per CU)
#define TPT  8              // tiles per block: 256*8 = 2048 tiles

typedef __attribute__((ext_vector_type(8))) short  bf16x8;
typedef __attribute__((ext_vector_type(4))) float  f32x4;

__device__ __forceinline__ ushort f2bf(float f) {
    __hip_bfloat16 h = __float2bfloat16(f);
    return *reinterpret_cast<ushort*>(&h);
}
__device__ __forceinline__ uint pkbf(float a, float b) {
    return (uint)f2bf(a) | ((uint)f2bf(b) << 16);
}
__device__ __forceinline__ float fast_tanh(float x) {
    float e = __expf(2.0f * x);
    return 1.0f - 2.0f / (e + 1.0f);
}

// ---------------- kernel 1: pack W[:, 0:512] to bf16 in FRAGMENT order.
// Layout: [ot(48)][ks(16)][lane(64)][j(8)]
//   o = ot*16 + (lane&15), k = ks*32 + (lane>>4)*8 + j
__global__ void pack_w(const float* __restrict__ W, short* __restrict__ wpk) {
    int t = blockIdx.x * 256 + threadIdx.x;       // over 48*16*64
    if (t >= 48 * 16 * 64) return;
    int lane = t & 63;
    int ks   = (t >> 6) & 15;
    int ot   = t >> 10;
    int o  = ot * 16 + (lane & 15);
    int kb = ks * 32 + (lane >> 4) * 8;
    const float* src = W + (size_t)o * H3_ + kb;
    float4 a = ((const float4*)src)[0];
    float4 b = ((const float4*)src)[1];
    union { bf16x8 v; uint4 u; } pk;
    pk.u.x = pkbf(a.x, a.y);
    pk.u.y = pkbf(a.z, a.w);
    pk.u.z = pkbf(b.x, b.y);
    pk.u.w = pkbf(b.z, b.w);
    *(bf16x8*)(wpk + (size_t)t * 8) = pk.v;
}

// ---------------- kernel 2: bias[b,o] = sum_k W[o,512+k] * dec[b,k]  (fp32)
__global__ void bias_k(const float* __restrict__ W, const float* __restrict__ dec,
                       float* __restrict__ bias) {
    int idx = blockIdx.x * 256 + threadIdx.x;     // over 64*768
    if (idx >= B_ * H3_) return;
    int b = idx / H3_;
    int o = idx - b * H3_;
    const float4* wr = (const float4*)(W + (size_t)o * H3_ + 2 * H_);
    const float4* dv = (const float4*)(dec + (size_t)b * H_);
    float s = 0.f;
#pragma unroll 8
    for (int k = 0; k < H_ / 4; ++k) {
        float4 a = wr[k], d = dv[k];
        s += a.x * d.x + a.y * d.y + a.z * d.z + a.w * d.w;
    }
    bias[idx] = s;
}

// ---------------- kernel 3: fused score GEMM.
// 8 waves, 1 block/CU, double-buffered 64KB A-tiles in LDS, persistent over
// 8 consecutive tiles. Stage(t+1) overlaps compute(t); one barrier per tile.
// Per tile: 2 passes; wave covers cols wave*96 + p*48 .. +47 (3 o-tiles).
__global__ __launch_bounds__(512, 2)
void score_k(const float* __restrict__ stat, const float* __restrict__ dyn,
             const short* __restrict__ wpk, const float* __restrict__ bias,
             const float* __restrict__ v, float* __restrict__ scores) {
    __shared__ short aT[2 * MT * K_];        // 2 x 64 KB
    __shared__ float sred[2][8][MT];         // parity-alternated, 4 KB

    const int tid  = threadIdx.x;
    const int wave = tid >> 6;
    const int lane = tid & 63;
    const int lr   = lane & 15;              // A: row-in-16 ; B/C: col-in-16
    const int lg   = lane >> 4;              // k-group (8 elems each)

    // staging geometry: batch b, unit i: row = (b*4+i)*8 + wave, k = lane*8
    const int kcol = lane * 8;
    const float* srcbase = (kcol < 256) ? (stat + kcol) : (dyn + (kcol - 256));

    float4 f0[4], f1[4];                     // 4 units (8 float4) in flight

    auto loadq = [&](int bat, int gpos0) {
#pragma unroll
        for (int i = 0; i < 4; ++i) {
            int row = (bat * 4 + i) * 8 + wave;
            const float4* p = (const float4*)(srcbase + (size_t)(gpos0 + row) * H_);
            f0[i] = p[0];
            f1[i] = p[1];
        }
    };
    auto writeb = [&](int bat, int buf) {
#pragma unroll
        for (int i = 0; i < 4; ++i) {
            int row = (bat * 4 + i) * 8 + wave;
            uint4 pk;
            pk.x = pkbf(f0[i].x, f0[i].y);
            pk.y = pkbf(f0[i].z, f0[i].w);
            pk.z = pkbf(f1[i].x, f1[i].y);
            pk.w = pkbf(f1[i].z, f1[i].w);
            int off = buf * 65536 + (((row << 10) + (lane << 4)) ^ ((row & 7) << 4));
            *(uint4*)((char*)aT + off) = pk;
        }
    };

    // prologue: stage tile 0 into buffer 0
    {
        const int g0 = blockIdx.x * (TPT * MT);
        loadq(0, g0); writeb(0, 0);
        loadq(1, g0); writeb(1, 0);
    }
    __syncthreads();

#pragma unroll 1
    for (int t = 0; t < TPT; ++t) {
        const int pos0 = (blockIdx.x * TPT + t) * MT;
        const int bidx = pos0 >> 11;         // tile never crosses b
        const int pos0n = pos0 + MT;         // next tile (consecutive)
        const int cbuf = (t & 1) * 65536;
        const int nbufi = (t & 1) ^ 1;

        float sacc[4][4];
#pragma unroll
        for (int mi = 0; mi < 4; ++mi)
#pragma unroll
            for (int j = 0; j < 4; ++j) sacc[mi][j] = 0.f;

        if (t < TPT - 1) loadq(0, pos0n);    // issue early: hides under pass 0

#pragma unroll
        for (int p = 0; p < 2; ++p) {
            f32x4 acc[4][3];
#pragma unroll
            for (int mi = 0; mi < 4; ++mi)
#pragma unroll
                for (int ni = 0; ni < 3; ++ni) acc[mi][ni] = (f32x4)0.f;

            const short* wp0 = wpk + ((size_t)((wave * 6 + p * 3) * 16) * 64 + lane) * 8;

            bf16x8 bcur[3];
#pragma unroll
            for (int ni = 0; ni < 3; ++ni)
                bcur[ni] = *(const bf16x8*)(wp0 + ni * 8192);

#pragma unroll 4
            for (int ks = 0; ks < 16; ++ks) {
                bf16x8 bnxt[3];
                const int ksn = (ks < 15) ? ks + 1 : 15;
#pragma unroll
                for (int ni = 0; ni < 3; ++ni)
                    bnxt[ni] = *(const bf16x8*)(wp0 + ni * 8192 + ksn * 512);
                const int kb2 = ks * 64 + lg * 16;
                __builtin_amdgcn_s_setprio(1);
#pragma unroll
                for (int mi = 0; mi < 4; ++mi) {
                    int off = cbuf + ((((mi * 16 + lr) << 10) + kb2) ^ ((lr & 7) << 4));
                    bf16x8 afr = *(const bf16x8*)((const char*)aT + off);
#pragma unroll
                    for (int ni = 0; ni < 3; ++ni)
                        acc[mi][ni] = __builtin_amdgcn_mfma_f32_16x16x32_bf16(
                            afr, bcur[ni], acc[mi][ni], 0, 0, 0);
                }
                __builtin_amdgcn_s_setprio(0);
#pragma unroll
                for (int ni = 0; ni < 3; ++ni) bcur[ni] = bnxt[ni];
            }

            // epilogue: sacc += v * tanh(acc + bias)
#pragma unroll
            for (int ni = 0; ni < 3; ++ni) {
                int o = wave * 96 + p * 48 + ni * 16 + lr;
                float bv = bias[bidx * H3_ + o];
                float vv = v[o];
#pragma unroll
                for (int mi = 0; mi < 4; ++mi)
#pragma unroll
                    for (int j = 0; j < 4; ++j)
                        sacc[mi][j] += vv * fast_tanh(acc[mi][ni][j] + bv);
            }

            // staging milestones into the inactive buffer (no barrier needed)
            if (t < TPT - 1) {
                if (p == 0) { writeb(0, nbufi); loadq(1, pos0n); }
                else        { writeb(1, nbufi); }
            }
        }

        // reduce over the 16 column-lanes; rows live at mi*16 + lg*4 + j
#pragma unroll
        for (int mi = 0; mi < 4; ++mi)
#pragma unroll
            for (int j = 0; j < 4; ++j) {
                float x = sacc[mi][j];
                x += __shfl_xor(x, 1);
                x += __shfl_xor(x, 2);
                x += __shfl_xor(x, 4);
                x += __shfl_xor(x, 8);
                sacc[mi][j] = x;
            }
        if (lr == 0) {
#pragma unroll
            for (int mi = 0; mi < 4; ++mi)
#pragma unroll
                for (int j = 0; j < 4; ++j)
                    sred[t & 1][wave][mi * 16 + lg * 4 + j] = sacc[mi][j];
        }
        __syncthreads();   // sred visible AND buf(t+1) staging complete
        if (tid < MT) {
            float s = 0.f;
#pragma unroll
            for (int w = 0; w < 8; ++w) s += sred[t & 1][w][tid];
            scores[pos0 + tid] = s;
        }
    }
}

// ---------------- kernel 4: softmax over S=2048 per b, in place on d_out
__global__ void softmax_k(float* __restrict__ out) {
    const int b = blockIdx.x;
    float* row = out + (size_t)b * S_;
    const int tid  = threadIdx.x;          // 256
    const int wave = tid >> 6;
    const int lane = tid & 63;

    float vals[8];
    float m = -1e30f;
#pragma unroll
    for (int i = 0; i < 8; ++i) {
        vals[i] = row[tid + i * 256];
        m = fmaxf(m, vals[i]);
    }
#pragma unroll
    for (int off = 32; off >= 1; off >>= 1) m = fmaxf(m, __shfl_xor(m, off));
    __shared__ float redm[4];
    __shared__ float reds[4];
    if (lane == 0) redm[wave] = m;
    __syncthreads();
    m = fmaxf(fmaxf(redm[0], redm[1]), fmaxf(redm[2], redm[3]));

    float s = 0.f;
#pragma unroll
    for (int i = 0; i < 8; ++i) {
        vals[i] = __expf(vals[i] - m);
        s += vals[i];
    }
#pragma unroll
    for (int off = 32; off >= 1; off >>= 1) s += __shfl_xor(s, off);
    if (lane == 0) reds[wave] = s;
    __syncthreads();
    s = reds[0] + reds[1] + reds[2] + reds[3];
    float inv = 1.0f / s;
#pragma unroll
    for (int i = 0; i < 8; ++i) row[tid + i * 256] = vals[i] * inv;
}

extern "C" void kernel_launch(void* const* d_in, const int* in_sizes, int n_in,
                              void* d_out, int out_size, void* d_ws, size_t ws_size,
                              hipStream_t stream) {
    const float* stat = (const float*)d_in[0];   // [64,2048,256]
    const float* dyn  = (const float*)d_in[1];   // [64,2048,256]
    const float* dec  = (const float*)d_in[2];   // [64,256]
    const float* v    = (const float*)d_in[3];   // [1,768]
    const float* W    = (const float*)d_in[4];   // [768,768]
    float* out = (float*)d_out;                  // [64,2048]

    short* wpk  = (short*)d_ws;                                 // 786432 B
    float* bias = (float*)((char*)d_ws + (size_t)H3_ * K_ * 2); // 196608 B

    pack_w <<<(48 * 16 * 64 + 255) / 256, 256, 0, stream>>>(W, wpk);
    bias_k <<<(B_ * H3_ + 255) / 256, 256, 0, stream>>>(W, dec, bias);
    score_k<<<NBLK, 512, 0, stream>>>(stat, dyn, wpk, bias, v, out);
    softmax_k<<<B_, 256, 0, stream>>>(out);
}